// Round 8
// baseline (291.697 us; speedup 1.0000x reference)
//
#include <hip/hip_runtime.h>
#include <hip/hip_bf16.h>

#define NFEAT 128
#define ALPHA 0.2f
#define CBSH 10          // coarse bucket = 1024 nodes
#define CB   1024
#define NBMAX 128        // max coarse buckets (N=100000 -> 98)
#define TILE 4096        // edges per partition tile

// bf16 pair pack/unpack (RN-even)
__device__ inline unsigned int packbf2(float a, float b) {
  unsigned int ua = __float_as_uint(a), ub = __float_as_uint(b);
  ua = (ua + 0x7fffu + ((ua >> 16) & 1u)) >> 16;
  ub = (ub + 0x7fffu + ((ub >> 16) & 1u)) >> 16;
  return ua | (ub << 16);
}
__device__ inline void unpackbf2(unsigned int u, float& lo, float& hi) {
  lo = __uint_as_float(u << 16);
  hi = __uint_as_float(u & 0xffff0000u);
}

// ---------------- CSR build (bucketed, coalesced) ----------------

__global__ __launch_bounds__(256) void k_bhist(const int* __restrict__ dst, int* __restrict__ bcnt,
                                               int E, int nbuk) {
  __shared__ int lh[NBMAX];
  int t = threadIdx.x;
  if (t < NBMAX) lh[t] = 0;
  __syncthreads();
  int stride = gridDim.x * 256;
  int E4 = E >> 2;
  const int4* d4 = (const int4*)dst;
  for (int e = blockIdx.x * 256 + t; e < E4; e += stride) {
    int4 v = d4[e];
    atomicAdd(&lh[v.x >> CBSH], 1);
    atomicAdd(&lh[v.y >> CBSH], 1);
    atomicAdd(&lh[v.z >> CBSH], 1);
    atomicAdd(&lh[v.w >> CBSH], 1);
  }
  for (int e = (E4 << 2) + blockIdx.x * 256 + t; e < E; e += stride)
    atomicAdd(&lh[dst[e] >> CBSH], 1);
  __syncthreads();
  if (t < nbuk && lh[t]) atomicAdd(&bcnt[t], lh[t]);
}

__global__ __launch_bounds__(NBMAX) void k_bscan(const int* __restrict__ bcnt, int* __restrict__ brow,
                                                 int* __restrict__ bfill, int nbuk, int E) {
  __shared__ int sc[NBMAX];
  int t = threadIdx.x;
  int v = (t < nbuk) ? bcnt[t] : 0;
  sc[t] = v;
  __syncthreads();
  for (int o = 1; o < NBMAX; o <<= 1) {
    int u = (t >= o) ? sc[t - o] : 0;
    __syncthreads();
    sc[t] += u;
    __syncthreads();
  }
  int ex = sc[t] - v;
  if (t < nbuk) { brow[t] = ex; bfill[t] = ex; }
  if (t == 0) brow[nbuk] = E;
}

__global__ __launch_bounds__(256) void k_bpart(const int* __restrict__ src, const int* __restrict__ dst,
    int* __restrict__ bfill, unsigned int* __restrict__ pairs, int E) {
  __shared__ unsigned long long sp[TILE];           // 32 KB
  __shared__ int lh[NBMAX], lo[NBMAX], gb[NBMAX], lf[NBMAX];
  int t = threadIdx.x;
  int tb = blockIdx.x * TILE;
  int cnt = E - tb; if (cnt > TILE) cnt = TILE;
  if (t < NBMAX) { lh[t] = 0; lf[t] = 0; }
  __syncthreads();
  int es[TILE / 256], ed[TILE / 256];
  #pragma unroll
  for (int k = 0; k < TILE / 256; ++k) {
    int li = k * 256 + t;
    bool v = li < cnt;
    es[k] = v ? src[tb + li] : 0;
    ed[k] = v ? dst[tb + li] : -1;
    if (v) atomicAdd(&lh[ed[k] >> CBSH], 1);
  }
  __syncthreads();
  if (t < NBMAX) lo[t] = lh[t];
  __syncthreads();
  for (int o = 1; o < NBMAX; o <<= 1) {
    int u = (t < NBMAX && t >= o) ? lo[t - o] : 0;
    __syncthreads();
    if (t < NBMAX) lo[t] += u;
    __syncthreads();
  }
  if (t < NBMAX) {
    lo[t] -= lh[t];
    if (lh[t] > 0) gb[t] = atomicAdd(&bfill[t], lh[t]);
  }
  __syncthreads();
  #pragma unroll
  for (int k = 0; k < TILE / 256; ++k) if (ed[k] >= 0) {
    int bb = ed[k] >> CBSH;
    int r = atomicAdd(&lf[bb], 1);
    sp[lo[bb] + r] = ((unsigned long long)(unsigned int)es[k] << 32) | (unsigned int)ed[k];
  }
  __syncthreads();
  for (int i = t; i < cnt; i += 256) {
    unsigned long long p = sp[i];
    unsigned int d = (unsigned int)p;
    unsigned int s = (unsigned int)(p >> 32);
    int bb = d >> CBSH;
    pairs[gb[bb] + (i - lo[bb])] = (s << CBSH) | (d & (CB - 1));
  }
}

// per-bucket degrees -> rowptr, dis, global fill cursors (one block per bucket)
__global__ __launch_bounds__(256) void k_ndeg(const unsigned int* __restrict__ pairs,
    const int* __restrict__ brow, int* __restrict__ rowptr, int* __restrict__ fillc,
    float* __restrict__ dis, int n, int E) {
  __shared__ int deg[CB];
  __shared__ int wsum[256];
  int b = blockIdx.x, t = threadIdx.x;
  int beg = brow[b], end = brow[b + 1];
  #pragma unroll
  for (int k = 0; k < CB / 256; ++k) deg[t + k * 256] = 0;
  __syncthreads();
  for (int i = beg + t; i < end; i += 256)
    atomicAdd(&deg[pairs[i] & (CB - 1)], 1);
  __syncthreads();
  int s0 = deg[4 * t], s1 = deg[4 * t + 1], s2 = deg[4 * t + 2], s3 = deg[4 * t + 3];
  int tsum = s0 + s1 + s2 + s3;
  wsum[t] = tsum;
  __syncthreads();
  for (int o = 1; o < 256; o <<= 1) {
    int u = (t >= o) ? wsum[t - o] : 0;
    __syncthreads();
    wsum[t] += u;
    __syncthreads();
  }
  int ex = wsum[t] - tsum;
  int base_node = (b << CBSH) + 4 * t;
  int p0 = beg + ex, p1 = p0 + s0, p2 = p1 + s1, p3 = p2 + s2;
  if (base_node + 0 < n) { rowptr[base_node + 0] = p0; fillc[base_node + 0] = p0; dis[base_node + 0] = rsqrtf((float)(s0 + 1)); }
  if (base_node + 1 < n) { rowptr[base_node + 1] = p1; fillc[base_node + 1] = p1; dis[base_node + 1] = rsqrtf((float)(s1 + 1)); }
  if (base_node + 2 < n) { rowptr[base_node + 2] = p2; fillc[base_node + 2] = p2; dis[base_node + 2] = rsqrtf((float)(s2 + 1)); }
  if (base_node + 3 < n) { rowptr[base_node + 3] = p3; fillc[base_node + 3] = p3; dis[base_node + 3] = rsqrtf((float)(s3 + 1)); }
  if (b == 0 && t == 0) rowptr[n] = E;
}

// scatter srcs into per-node CSR slots; 8 blocks per bucket, global atomic cursors
__global__ __launch_bounds__(256) void k_fill2(const unsigned int* __restrict__ pairs,
    const int* __restrict__ brow, int* __restrict__ fillc, int* __restrict__ lst) {
  int b = blockIdx.x >> 3, sl = blockIdx.x & 7;
  int beg = brow[b], end = brow[b + 1];
  int base = b << CBSH;
  for (int i = beg + sl * 256 + (int)threadIdx.x; i < end; i += 8 * 256) {
    unsigned int u = pairs[i];
    int p = atomicAdd(&fillc[base | (u & (CB - 1))], 1);
    lst[p] = (int)(u >> CBSH);
  }
}

// ---------------- skinny GEMMs: wave-uniform W (scalar loads), lane = row ----------------

template<int K, int OW, bool HAS_BIAS, bool LEAKY, bool SCALE, bool OBF>
__global__ __launch_bounds__(256) void k_gemm(const float* __restrict__ A,
    const float* __restrict__ W, const float* __restrict__ bias,
    const float* __restrict__ dis, void* __restrict__ outv, int n) {
  constexpr int WPC = OW / 16;               // waves per column span (4 or 2)
  constexpr int RPB = (4 / WPC) * 64;        // rows per block (64 or 128)
  int w = threadIdx.x >> 6, lane = threadIdx.x & 63;
  int og = __builtin_amdgcn_readfirstlane((w % WPC) * 16);
  int row = blockIdx.x * RPB + (w / WPC) * 64 + lane;
  bool ok = row < n;
  int rowc = ok ? row : 0;
  float acc[16];
  #pragma unroll
  for (int j = 0; j < 16; ++j) acc[j] = 0.f;
  const float4* a4 = (const float4*)(A + (size_t)rowc * K);
  const float* Wg = W + og;
  #pragma unroll 4
  for (int k4 = 0; k4 < K / 4; ++k4) {
    float4 xv = a4[k4];
    #pragma unroll
    for (int kk = 0; kk < 4; ++kk) {
      const float* wr = Wg + (k4 * 4 + kk) * OW;
      float xk = kk == 0 ? xv.x : kk == 1 ? xv.y : kk == 2 ? xv.z : xv.w;
      #pragma unroll
      for (int j = 0; j < 16; ++j) acc[j] += xk * wr[j];
    }
  }
  float sc = SCALE ? dis[rowc] : 1.f;
  #pragma unroll
  for (int j = 0; j < 16; ++j) {
    float v = acc[j];
    if (HAS_BIAS) v += bias[og + j];
    if (SCALE) v *= sc;
    if (LEAKY) v = v > 0.f ? v : ALPHA * v;
    acc[j] = v;
  }
  if (!ok) return;
  if (OBF) {
    uint4 p0, p1;
    p0.x = packbf2(acc[0], acc[1]);  p0.y = packbf2(acc[2], acc[3]);
    p0.z = packbf2(acc[4], acc[5]);  p0.w = packbf2(acc[6], acc[7]);
    p1.x = packbf2(acc[8], acc[9]);  p1.y = packbf2(acc[10], acc[11]);
    p1.z = packbf2(acc[12], acc[13]); p1.w = packbf2(acc[14], acc[15]);
    uint4* o = (uint4*)((unsigned int*)outv + (((size_t)row * OW + og) >> 1));
    o[0] = p0; o[1] = p1;
  } else {
    float4* o = (float4*)((float*)outv + (size_t)row * OW + og);
    o[0] = float4{acc[0], acc[1], acc[2], acc[3]};
    o[1] = float4{acc[4], acc[5], acc[6], acc[7]};
    o[2] = float4{acc[8], acc[9], acc[10], acc[11]};
    o[3] = float4{acc[12], acc[13], acc[14], acc[15]};
  }
}

// ---------------- aggregation: wave per node, bf16 uint4 gathers ----------------

// conv1: g row = 64 bf16 = 8 uint4. 8 lanes/edge -> 8 edges/step, 4x unroll (32 gathers in flight)
__global__ __launch_bounds__(256) void k_agg1(const uint4* __restrict__ g4,
    const float* __restrict__ dis, const float* __restrict__ bias,
    const int* __restrict__ rowptr, const int* __restrict__ lst,
    float* __restrict__ h, int n) {
  int wid = (blockIdx.x * 256 + threadIdx.x) >> 6;
  if (wid >= n) return;
  int lane = threadIdx.x & 63;
  int c = lane & 7, q = lane >> 3;
  float a[8];
  #pragma unroll
  for (int j = 0; j < 8; ++j) a[j] = 0.f;
  if (q == 0) {
    uint4 u = g4[(size_t)wid * 8 + c];
    unpackbf2(u.x, a[0], a[1]); unpackbf2(u.y, a[2], a[3]);
    unpackbf2(u.z, a[4], a[5]); unpackbf2(u.w, a[6], a[7]);
  }
  int beg = rowptr[wid], cnt = rowptr[wid + 1] - beg;
  for (int o = q; o < cnt; o += 32) {
    int s[4]; uint4 u[4];
    #pragma unroll
    for (int k = 0; k < 4; ++k)
      s[k] = (o + 8 * k < cnt) ? lst[beg + o + 8 * k] : -1;
    #pragma unroll
    for (int k = 0; k < 4; ++k)
      u[k] = (s[k] >= 0) ? g4[(size_t)s[k] * 8 + c] : uint4{0u, 0u, 0u, 0u};
    #pragma unroll
    for (int k = 0; k < 4; ++k) {
      float l, hv;
      unpackbf2(u[k].x, l, hv); a[0] += l; a[1] += hv;
      unpackbf2(u[k].y, l, hv); a[2] += l; a[3] += hv;
      unpackbf2(u[k].z, l, hv); a[4] += l; a[5] += hv;
      unpackbf2(u[k].w, l, hv); a[6] += l; a[7] += hv;
    }
  }
  #pragma unroll
  for (int j = 0; j < 8; ++j) {
    a[j] += __shfl_xor(a[j], 32);
    a[j] += __shfl_xor(a[j], 16);
    a[j] += __shfl_xor(a[j], 8);
  }
  if (q == 0) {
    float d = dis[wid];
    float vb[8];
    #pragma unroll
    for (int j = 0; j < 8; ++j) {
      float v = d * a[j] + bias[8 * c + j];
      vb[j] = v > 0.f ? v : 0.f;
    }
    float4* hp = (float4*)(h + (size_t)wid * 64 + 8 * c);
    hp[0] = float4{vb[0], vb[1], vb[2], vb[3]};
    hp[1] = float4{vb[4], vb[5], vb[6], vb[7]};
  }
}

// conv2 + final linear: g row = 32 bf16 = 4 uint4. 4 lanes/edge -> 16 edges/step, 2x unroll
__global__ __launch_bounds__(256) void k_agg2(const uint4* __restrict__ g4,
    const float* __restrict__ dis, const float* __restrict__ bias,
    const float* __restrict__ W3, const float* __restrict__ b3,
    const int* __restrict__ rowptr, const int* __restrict__ lst,
    float* __restrict__ out, int n) {
  int wid = (blockIdx.x * 256 + threadIdx.x) >> 6;
  if (wid >= n) return;
  int lane = threadIdx.x & 63;
  int c = lane & 3, q = lane >> 2;
  float a[8];
  #pragma unroll
  for (int j = 0; j < 8; ++j) a[j] = 0.f;
  if (q == 0) {
    uint4 u = g4[(size_t)wid * 4 + c];
    unpackbf2(u.x, a[0], a[1]); unpackbf2(u.y, a[2], a[3]);
    unpackbf2(u.z, a[4], a[5]); unpackbf2(u.w, a[6], a[7]);
  }
  int beg = rowptr[wid], cnt = rowptr[wid + 1] - beg;
  for (int o = q; o < cnt; o += 32) {
    int s[2]; uint4 u[2];
    #pragma unroll
    for (int k = 0; k < 2; ++k)
      s[k] = (o + 16 * k < cnt) ? lst[beg + o + 16 * k] : -1;
    #pragma unroll
    for (int k = 0; k < 2; ++k)
      u[k] = (s[k] >= 0) ? g4[(size_t)s[k] * 4 + c] : uint4{0u, 0u, 0u, 0u};
    #pragma unroll
    for (int k = 0; k < 2; ++k) {
      float l, hv;
      unpackbf2(u[k].x, l, hv); a[0] += l; a[1] += hv;
      unpackbf2(u[k].y, l, hv); a[2] += l; a[3] += hv;
      unpackbf2(u[k].z, l, hv); a[4] += l; a[5] += hv;
      unpackbf2(u[k].w, l, hv); a[6] += l; a[7] += hv;
    }
  }
  #pragma unroll
  for (int j = 0; j < 8; ++j) {
    a[j] += __shfl_xor(a[j], 32);
    a[j] += __shfl_xor(a[j], 16);
    a[j] += __shfl_xor(a[j], 8);
    a[j] += __shfl_xor(a[j], 4);
  }
  float d = dis[wid];
  float r = 0.f;
  #pragma unroll
  for (int j = 0; j < 8; ++j) {
    float v = d * a[j] + bias[8 * c + j];
    v = v > 0.f ? v : 0.f;
    r += v * W3[8 * c + j];
  }
  r += __shfl_xor(r, 2);
  r += __shfl_xor(r, 1);
  if (lane == 0) out[wid] = r + b3[0];
}

// ---------------- launch ----------------

extern "C" void kernel_launch(void* const* d_in, const int* in_sizes, int n_in,
                              void* d_out, int out_size, void* d_ws, size_t ws_size,
                              hipStream_t stream) {
  (void)n_in; (void)out_size; (void)ws_size;
  const float* x  = (const float*)d_in[0];
  const int*   ei = (const int*)d_in[2];
  const float* W0 = (const float*)d_in[3];
  const float* b0 = (const float*)d_in[4];
  const float* W1 = (const float*)d_in[5];
  const float* b1 = (const float*)d_in[6];
  const float* W2 = (const float*)d_in[7];
  const float* b2 = (const float*)d_in[8];
  const float* W3 = (const float*)d_in[9];
  const float* b3 = (const float*)d_in[10];
  float* out = (float*)d_out;
  int N = in_sizes[0] / NFEAT;
  int E = in_sizes[2] / 2;
  const int* src = ei;
  const int* dst = ei + E;
  int nbuk = (N + CB - 1) / CB;

  char* ws = (char*)d_ws;
  size_t off = 0;
  auto alloc = [&](size_t bytes) -> char* {
    char* p = ws + off;
    off += (bytes + 255) & ~(size_t)255;
    return p;
  };
  int*   bcnt  = (int*)alloc((size_t)NBMAX * 4);
  int*   brow  = (int*)alloc((size_t)(NBMAX + 1) * 4);
  int*   bfill = (int*)alloc((size_t)NBMAX * 4);
  int*   rowp  = (int*)alloc((size_t)(N + 1) * 4);
  int*   fillc = (int*)alloc((size_t)N * 4);
  float* dis   = (float*)alloc((size_t)N * 4);
  unsigned int* pairs = (unsigned int*)alloc((size_t)E * 4);
  int*   lst   = (int*)alloc((size_t)E * 4);
  float* bufA  = (float*)alloc((size_t)N * 64 * 4);          // h0, then h1 (fp32)
  unsigned int* bufG = (unsigned int*)alloc((size_t)N * 32 * 4);  // g1 then g2 (bf16 packed)

  hipMemsetAsync(bcnt, 0, (size_t)NBMAX * 4, stream);
  k_bhist<<<512, 256, 0, stream>>>(dst, bcnt, E, nbuk);
  k_bscan<<<1, NBMAX, 0, stream>>>(bcnt, brow, bfill, nbuk, E);
  k_bpart<<<(E + TILE - 1) / TILE, 256, 0, stream>>>(src, dst, bfill, pairs, E);
  k_ndeg<<<nbuk, 256, 0, stream>>>(pairs, brow, rowp, fillc, dis, N, E);
  k_fill2<<<nbuk * 8, 256, 0, stream>>>(pairs, brow, fillc, lst);

  // h0 = leaky_relu(x@W0 + b0) -> bufA (fp32)
  k_gemm<NFEAT, 64, true, true, false, false><<<(N + 63) / 64, 256, 0, stream>>>(x, W0, b0, nullptr, bufA, N);
  // g1 = (h0@W1)*dis -> bufG (bf16)
  k_gemm<64, 64, false, false, true, true><<<(N + 63) / 64, 256, 0, stream>>>(bufA, W1, nullptr, dis, bufG, N);
  // h1 = relu(dis*(g1[d] + sum g1[s]) + b1) -> bufA (fp32)
  k_agg1<<<(N + 3) / 4, 256, 0, stream>>>((const uint4*)bufG, dis, b1, rowp, lst, bufA, N);
  // g2 = (h1@W2)*dis -> bufG (bf16)
  k_gemm<64, 32, false, false, true, true><<<(N + 127) / 128, 256, 0, stream>>>(bufA, W2, nullptr, dis, bufG, N);
  // out = relu(dis*(g2[d] + sum g2[s]) + b2) @ W3 + b3
  k_agg2<<<(N + 3) / 4, 256, 0, stream>>>((const uint4*)bufG, dis, b2, W3, b3, rowp, lst, out, N);
}

// Round 9
// 212.455 us; speedup vs baseline: 1.3730x; 1.3730x over previous
//
#include <hip/hip_runtime.h>
#include <hip/hip_bf16.h>

#define NFEAT 128
#define ALPHA 0.2f
#define CBSH 10          // coarse bucket = 1024 nodes
#define CB   1024
#define NBMAX 128        // max coarse buckets (N=100000 -> 98)
#define TILE 4096        // edges per partition tile

// bf16 pair pack/unpack (RN-even)
__device__ inline unsigned int packbf2(float a, float b) {
  unsigned int ua = __float_as_uint(a), ub = __float_as_uint(b);
  ua = (ua + 0x7fffu + ((ua >> 16) & 1u)) >> 16;
  ub = (ub + 0x7fffu + ((ub >> 16) & 1u)) >> 16;
  return ua | (ub << 16);
}
__device__ inline void unpackbf2(unsigned int u, float& lo, float& hi) {
  lo = __uint_as_float(u << 16);
  hi = __uint_as_float(u & 0xffff0000u);
}

// ---------------- CSR build (bucketed, coalesced) ----------------

__global__ __launch_bounds__(256) void k_bhist(const int* __restrict__ dst, int* __restrict__ bcnt,
                                               int E, int nbuk) {
  __shared__ int lh[NBMAX];
  int t = threadIdx.x;
  if (t < NBMAX) lh[t] = 0;
  __syncthreads();
  int stride = gridDim.x * 256;
  int E4 = E >> 2;
  const int4* d4 = (const int4*)dst;
  for (int e = blockIdx.x * 256 + t; e < E4; e += stride) {
    int4 v = d4[e];
    atomicAdd(&lh[v.x >> CBSH], 1);
    atomicAdd(&lh[v.y >> CBSH], 1);
    atomicAdd(&lh[v.z >> CBSH], 1);
    atomicAdd(&lh[v.w >> CBSH], 1);
  }
  for (int e = (E4 << 2) + blockIdx.x * 256 + t; e < E; e += stride)
    atomicAdd(&lh[dst[e] >> CBSH], 1);
  __syncthreads();
  if (t < nbuk && lh[t]) atomicAdd(&bcnt[t], lh[t]);
}

__global__ __launch_bounds__(NBMAX) void k_bscan(const int* __restrict__ bcnt, int* __restrict__ brow,
                                                 int* __restrict__ bfill, int nbuk, int E) {
  __shared__ int sc[NBMAX];
  int t = threadIdx.x;
  int v = (t < nbuk) ? bcnt[t] : 0;
  sc[t] = v;
  __syncthreads();
  for (int o = 1; o < NBMAX; o <<= 1) {
    int u = (t >= o) ? sc[t - o] : 0;
    __syncthreads();
    sc[t] += u;
    __syncthreads();
  }
  int ex = sc[t] - v;
  if (t < nbuk) { brow[t] = ex; bfill[t] = ex; }
  if (t == 0) brow[nbuk] = E;
}

__global__ __launch_bounds__(256) void k_bpart(const int* __restrict__ src, const int* __restrict__ dst,
    int* __restrict__ bfill, unsigned int* __restrict__ pairs, int E) {
  __shared__ unsigned long long sp[TILE];           // 32 KB
  __shared__ int lh[NBMAX], lo[NBMAX], gb[NBMAX], lf[NBMAX];
  int t = threadIdx.x;
  int tb = blockIdx.x * TILE;
  int cnt = E - tb; if (cnt > TILE) cnt = TILE;
  if (t < NBMAX) { lh[t] = 0; lf[t] = 0; }
  __syncthreads();
  int es[TILE / 256], ed[TILE / 256];
  #pragma unroll
  for (int k = 0; k < TILE / 256; ++k) {
    int li = k * 256 + t;
    bool v = li < cnt;
    es[k] = v ? src[tb + li] : 0;
    ed[k] = v ? dst[tb + li] : -1;
    if (v) atomicAdd(&lh[ed[k] >> CBSH], 1);
  }
  __syncthreads();
  if (t < NBMAX) lo[t] = lh[t];
  __syncthreads();
  for (int o = 1; o < NBMAX; o <<= 1) {
    int u = (t < NBMAX && t >= o) ? lo[t - o] : 0;
    __syncthreads();
    if (t < NBMAX) lo[t] += u;
    __syncthreads();
  }
  if (t < NBMAX) {
    lo[t] -= lh[t];
    if (lh[t] > 0) gb[t] = atomicAdd(&bfill[t], lh[t]);
  }
  __syncthreads();
  #pragma unroll
  for (int k = 0; k < TILE / 256; ++k) if (ed[k] >= 0) {
    int bb = ed[k] >> CBSH;
    int r = atomicAdd(&lf[bb], 1);
    sp[lo[bb] + r] = ((unsigned long long)(unsigned int)es[k] << 32) | (unsigned int)ed[k];
  }
  __syncthreads();
  for (int i = t; i < cnt; i += 256) {
    unsigned long long p = sp[i];
    unsigned int d = (unsigned int)p;
    unsigned int s = (unsigned int)(p >> 32);
    int bb = d >> CBSH;
    pairs[gb[bb] + (i - lo[bb])] = (s << CBSH) | (d & (CB - 1));
  }
}

// per-bucket CSR finalize: degrees -> rowptr/dis, then block-local counting-sort scatter.
// ONE block per bucket (all writes to the bucket's lst region stay on one CU/XCD ->
// full-line writebacks; see R8 post-mortem), but 1024 threads for 4x parallelism.
__global__ __launch_bounds__(1024) void k_bcsr(const unsigned int* __restrict__ pairs,
    const int* __restrict__ brow, int* __restrict__ rowptr, int* __restrict__ lst,
    float* __restrict__ dis, int n, int E) {
  __shared__ int deg[CB];
  __shared__ int woff[16];
  int b = blockIdx.x, t = threadIdx.x;
  int lane = t & 63, w = t >> 6;
  int beg = brow[b], end = brow[b + 1];
  deg[t] = 0;
  __syncthreads();
  for (int i = beg + t; i < end; i += 1024)
    atomicAdd(&deg[pairs[i] & (CB - 1)], 1);
  __syncthreads();
  int d = deg[t];
  // inclusive scan within wave
  int v = d;
  #pragma unroll
  for (int o = 1; o < 64; o <<= 1) {
    int u = __shfl_up(v, o);
    if (lane >= o) v += u;
  }
  if (lane == 63) woff[w] = v;
  __syncthreads();
  if (w == 0) {
    int orig = (lane < 16) ? woff[lane] : 0;
    int s = orig;
    #pragma unroll
    for (int o = 1; o < 16; o <<= 1) {
      int u = __shfl_up(s, o);
      if (lane >= o) s += u;
    }
    if (lane < 16) woff[lane] = s - orig;   // exclusive wave offsets
  }
  __syncthreads();
  int pos = beg + (v - d) + woff[w];
  int node = (b << CBSH) + t;
  if (node < n) {
    rowptr[node] = pos;
    dis[node] = rsqrtf((float)(d + 1));
  }
  if (b == 0 && t == 0) rowptr[n] = E;
  deg[t] = pos;                              // reuse as fill cursor
  __syncthreads();
  for (int i = beg + t; i < end; i += 1024) {
    unsigned int u = pairs[i];
    int p = atomicAdd(&deg[u & (CB - 1)], 1);
    lst[p] = (int)(u >> CBSH);
  }
}

// ---------------- skinny GEMMs: wave-uniform W (scalar loads), lane = row ----------------

template<int K, int OW, bool HAS_BIAS, bool LEAKY, bool SCALE, bool OBF>
__global__ __launch_bounds__(256) void k_gemm(const float* __restrict__ A,
    const float* __restrict__ W, const float* __restrict__ bias,
    const float* __restrict__ dis, void* __restrict__ outv, int n) {
  constexpr int WPC = OW / 16;               // waves per column span (4 or 2)
  constexpr int RPB = (4 / WPC) * 64;        // rows per block (64 or 128)
  int w = threadIdx.x >> 6, lane = threadIdx.x & 63;
  int og = __builtin_amdgcn_readfirstlane((w % WPC) * 16);
  int row = blockIdx.x * RPB + (w / WPC) * 64 + lane;
  bool ok = row < n;
  int rowc = ok ? row : 0;
  float acc[16];
  #pragma unroll
  for (int j = 0; j < 16; ++j) acc[j] = 0.f;
  const float4* a4 = (const float4*)(A + (size_t)rowc * K);
  const float* Wg = W + og;
  #pragma unroll 4
  for (int k4 = 0; k4 < K / 4; ++k4) {
    float4 xv = a4[k4];
    #pragma unroll
    for (int kk = 0; kk < 4; ++kk) {
      const float* wr = Wg + (k4 * 4 + kk) * OW;
      float xk = kk == 0 ? xv.x : kk == 1 ? xv.y : kk == 2 ? xv.z : xv.w;
      #pragma unroll
      for (int j = 0; j < 16; ++j) acc[j] += xk * wr[j];
    }
  }
  float sc = SCALE ? dis[rowc] : 1.f;
  #pragma unroll
  for (int j = 0; j < 16; ++j) {
    float v = acc[j];
    if (HAS_BIAS) v += bias[og + j];
    if (SCALE) v *= sc;
    if (LEAKY) v = v > 0.f ? v : ALPHA * v;
    acc[j] = v;
  }
  if (!ok) return;
  if (OBF) {
    uint4 p0, p1;
    p0.x = packbf2(acc[0], acc[1]);  p0.y = packbf2(acc[2], acc[3]);
    p0.z = packbf2(acc[4], acc[5]);  p0.w = packbf2(acc[6], acc[7]);
    p1.x = packbf2(acc[8], acc[9]);  p1.y = packbf2(acc[10], acc[11]);
    p1.z = packbf2(acc[12], acc[13]); p1.w = packbf2(acc[14], acc[15]);
    uint4* o = (uint4*)((unsigned int*)outv + (((size_t)row * OW + og) >> 1));
    o[0] = p0; o[1] = p1;
  } else {
    float4* o = (float4*)((float*)outv + (size_t)row * OW + og);
    o[0] = float4{acc[0], acc[1], acc[2], acc[3]};
    o[1] = float4{acc[4], acc[5], acc[6], acc[7]};
    o[2] = float4{acc[8], acc[9], acc[10], acc[11]};
    o[3] = float4{acc[12], acc[13], acc[14], acc[15]};
  }
}

// ---------------- aggregation: wave per node, bf16 uint4 gathers ----------------

// conv1: g row = 64 bf16 = 8 uint4. 8 lanes/edge -> 8 edges/step, 4x unroll (32 gathers in flight)
__global__ __launch_bounds__(256) void k_agg1(const uint4* __restrict__ g4,
    const float* __restrict__ dis, const float* __restrict__ bias,
    const int* __restrict__ rowptr, const int* __restrict__ lst,
    float* __restrict__ h, int n) {
  int wid = (blockIdx.x * 256 + threadIdx.x) >> 6;
  if (wid >= n) return;
  int lane = threadIdx.x & 63;
  int c = lane & 7, q = lane >> 3;
  float a[8];
  #pragma unroll
  for (int j = 0; j < 8; ++j) a[j] = 0.f;
  if (q == 0) {
    uint4 u = g4[(size_t)wid * 8 + c];
    unpackbf2(u.x, a[0], a[1]); unpackbf2(u.y, a[2], a[3]);
    unpackbf2(u.z, a[4], a[5]); unpackbf2(u.w, a[6], a[7]);
  }
  int beg = rowptr[wid], cnt = rowptr[wid + 1] - beg;
  for (int o = q; o < cnt; o += 32) {
    int s[4]; uint4 u[4];
    #pragma unroll
    for (int k = 0; k < 4; ++k)
      s[k] = (o + 8 * k < cnt) ? lst[beg + o + 8 * k] : -1;
    #pragma unroll
    for (int k = 0; k < 4; ++k)
      u[k] = (s[k] >= 0) ? g4[(size_t)s[k] * 8 + c] : uint4{0u, 0u, 0u, 0u};
    #pragma unroll
    for (int k = 0; k < 4; ++k) {
      float l, hv;
      unpackbf2(u[k].x, l, hv); a[0] += l; a[1] += hv;
      unpackbf2(u[k].y, l, hv); a[2] += l; a[3] += hv;
      unpackbf2(u[k].z, l, hv); a[4] += l; a[5] += hv;
      unpackbf2(u[k].w, l, hv); a[6] += l; a[7] += hv;
    }
  }
  #pragma unroll
  for (int j = 0; j < 8; ++j) {
    a[j] += __shfl_xor(a[j], 32);
    a[j] += __shfl_xor(a[j], 16);
    a[j] += __shfl_xor(a[j], 8);
  }
  if (q == 0) {
    float d = dis[wid];
    float vb[8];
    #pragma unroll
    for (int j = 0; j < 8; ++j) {
      float v = d * a[j] + bias[8 * c + j];
      vb[j] = v > 0.f ? v : 0.f;
    }
    float4* hp = (float4*)(h + (size_t)wid * 64 + 8 * c);
    hp[0] = float4{vb[0], vb[1], vb[2], vb[3]};
    hp[1] = float4{vb[4], vb[5], vb[6], vb[7]};
  }
}

// conv2 + final linear: g row = 32 bf16 = 4 uint4. 4 lanes/edge -> 16 edges/step, 2x unroll
__global__ __launch_bounds__(256) void k_agg2(const uint4* __restrict__ g4,
    const float* __restrict__ dis, const float* __restrict__ bias,
    const float* __restrict__ W3, const float* __restrict__ b3,
    const int* __restrict__ rowptr, const int* __restrict__ lst,
    float* __restrict__ out, int n) {
  int wid = (blockIdx.x * 256 + threadIdx.x) >> 6;
  if (wid >= n) return;
  int lane = threadIdx.x & 63;
  int c = lane & 3, q = lane >> 2;
  float a[8];
  #pragma unroll
  for (int j = 0; j < 8; ++j) a[j] = 0.f;
  if (q == 0) {
    uint4 u = g4[(size_t)wid * 4 + c];
    unpackbf2(u.x, a[0], a[1]); unpackbf2(u.y, a[2], a[3]);
    unpackbf2(u.z, a[4], a[5]); unpackbf2(u.w, a[6], a[7]);
  }
  int beg = rowptr[wid], cnt = rowptr[wid + 1] - beg;
  for (int o = q; o < cnt; o += 32) {
    int s[2]; uint4 u[2];
    #pragma unroll
    for (int k = 0; k < 2; ++k)
      s[k] = (o + 16 * k < cnt) ? lst[beg + o + 16 * k] : -1;
    #pragma unroll
    for (int k = 0; k < 2; ++k)
      u[k] = (s[k] >= 0) ? g4[(size_t)s[k] * 4 + c] : uint4{0u, 0u, 0u, 0u};
    #pragma unroll
    for (int k = 0; k < 2; ++k) {
      float l, hv;
      unpackbf2(u[k].x, l, hv); a[0] += l; a[1] += hv;
      unpackbf2(u[k].y, l, hv); a[2] += l; a[3] += hv;
      unpackbf2(u[k].z, l, hv); a[4] += l; a[5] += hv;
      unpackbf2(u[k].w, l, hv); a[6] += l; a[7] += hv;
    }
  }
  #pragma unroll
  for (int j = 0; j < 8; ++j) {
    a[j] += __shfl_xor(a[j], 32);
    a[j] += __shfl_xor(a[j], 16);
    a[j] += __shfl_xor(a[j], 8);
    a[j] += __shfl_xor(a[j], 4);
  }
  float d = dis[wid];
  float r = 0.f;
  #pragma unroll
  for (int j = 0; j < 8; ++j) {
    float v = d * a[j] + bias[8 * c + j];
    v = v > 0.f ? v : 0.f;
    r += v * W3[8 * c + j];
  }
  r += __shfl_xor(r, 2);
  r += __shfl_xor(r, 1);
  if (lane == 0) out[wid] = r + b3[0];
}

// ---------------- launch ----------------

extern "C" void kernel_launch(void* const* d_in, const int* in_sizes, int n_in,
                              void* d_out, int out_size, void* d_ws, size_t ws_size,
                              hipStream_t stream) {
  (void)n_in; (void)out_size; (void)ws_size;
  const float* x  = (const float*)d_in[0];
  const int*   ei = (const int*)d_in[2];
  const float* W0 = (const float*)d_in[3];
  const float* b0 = (const float*)d_in[4];
  const float* W1 = (const float*)d_in[5];
  const float* b1 = (const float*)d_in[6];
  const float* W2 = (const float*)d_in[7];
  const float* b2 = (const float*)d_in[8];
  const float* W3 = (const float*)d_in[9];
  const float* b3 = (const float*)d_in[10];
  float* out = (float*)d_out;
  int N = in_sizes[0] / NFEAT;
  int E = in_sizes[2] / 2;
  const int* src = ei;
  const int* dst = ei + E;
  int nbuk = (N + CB - 1) / CB;

  char* ws = (char*)d_ws;
  size_t off = 0;
  auto alloc = [&](size_t bytes) -> char* {
    char* p = ws + off;
    off += (bytes + 255) & ~(size_t)255;
    return p;
  };
  int*   bcnt  = (int*)alloc((size_t)NBMAX * 4);
  int*   brow  = (int*)alloc((size_t)(NBMAX + 1) * 4);
  int*   bfill = (int*)alloc((size_t)NBMAX * 4);
  int*   rowp  = (int*)alloc((size_t)(N + 1) * 4);
  float* dis   = (float*)alloc((size_t)N * 4);
  unsigned int* pairs = (unsigned int*)alloc((size_t)E * 4);
  int*   lst   = (int*)alloc((size_t)E * 4);
  float* bufA  = (float*)alloc((size_t)N * 64 * 4);          // h0, then h1 (fp32)
  unsigned int* bufG = (unsigned int*)alloc((size_t)N * 32 * 4);  // g1 then g2 (bf16 packed)

  hipMemsetAsync(bcnt, 0, (size_t)NBMAX * 4, stream);
  k_bhist<<<512, 256, 0, stream>>>(dst, bcnt, E, nbuk);
  k_bscan<<<1, NBMAX, 0, stream>>>(bcnt, brow, bfill, nbuk, E);
  k_bpart<<<(E + TILE - 1) / TILE, 256, 0, stream>>>(src, dst, bfill, pairs, E);
  k_bcsr<<<nbuk, 1024, 0, stream>>>(pairs, brow, rowp, lst, dis, N, E);

  // h0 = leaky_relu(x@W0 + b0) -> bufA (fp32)
  k_gemm<NFEAT, 64, true, true, false, false><<<(N + 63) / 64, 256, 0, stream>>>(x, W0, b0, nullptr, bufA, N);
  // g1 = (h0@W1)*dis -> bufG (bf16)
  k_gemm<64, 64, false, false, true, true><<<(N + 63) / 64, 256, 0, stream>>>(bufA, W1, nullptr, dis, bufG, N);
  // h1 = relu(dis*(g1[d] + sum g1[s]) + b1) -> bufA (fp32)
  k_agg1<<<(N + 3) / 4, 256, 0, stream>>>((const uint4*)bufG, dis, b1, rowp, lst, bufA, N);
  // g2 = (h1@W2)*dis -> bufG (bf16)
  k_gemm<64, 32, false, false, true, true><<<(N + 127) / 128, 256, 0, stream>>>(bufA, W2, nullptr, dis, bufG, N);
  // out = relu(dis*(g2[d] + sum g2[s]) + b2) @ W3 + b3
  k_agg2<<<(N + 3) / 4, 256, 0, stream>>>((const uint4*)bufG, dis, b2, W3, b3, rowp, lst, out, N);
}